// Round 1
// baseline (172.196 us; speedup 1.0000x reference)
//
#include <hip/hip_runtime.h>

// DistributionLoss: per-pixel local std over zero-padded 7x7xC window of two
// [16,3,512,512] fp32 tensors, smooth-L1 mean between the std maps -> scalar.
//
// Separable box filter: t = sum_c x, t2 = sum_c x^2 staged in LDS (with halo),
// then 7-tap horizontal, then 7-tap vertical + std. Input 0's std tile is kept
// in LDS; input 1 fuses the smooth-L1 against it. One float atomicAdd per
// block (pre-scaled by 1/N_total).

#define K   7
#define PAD 3
#define TS  32            // output tile edge
#define HT  (TS + K - 1)  // 38 = tile + halo
#define NT  256

__global__ __launch_bounds__(NT) void dist_loss_kernel(
    const float* __restrict__ pred,
    const float* __restrict__ tgt,
    float* __restrict__ out)
{
    constexpr int   C = 3, H = 512, W = 512;
    constexpr float INV_N     = 1.0f / (C * K * K);              // 1/147
    constexpr float INV_TOTAL = 1.0f / (16.0f * 512.0f * 512.0f);

    __shared__ float sh_t [HT * HT];   // channel-summed x      (with halo)
    __shared__ float sh_t2[HT * HT];   // channel-summed x^2    (with halo)
    __shared__ float sh_h [HT * TS];   // horizontal 7-tap of t
    __shared__ float sh_h2[HT * TS];   // horizontal 7-tap of t2
    __shared__ float sh_sd[TS * TS];   // std of input 0

    const int    tid   = threadIdx.x;
    const int    tx0   = blockIdx.x * TS;
    const int    ty0   = blockIdx.y * TS;
    const int    b     = blockIdx.z;
    const size_t plane = (size_t)H * W;

    float acc = 0.0f;   // per-thread smooth-L1 partial

    #pragma unroll
    for (int which = 0; which < 2; ++which) {
        const float* base = (which == 0 ? pred : tgt) + (size_t)b * C * plane;

        // Phase 1: load halo tile, reduce over channels (zero padding = skip)
        for (int idx = tid; idx < HT * HT; idx += NT) {
            int ly = idx / HT, lx = idx - ly * HT;
            int gy = ty0 - PAD + ly;
            int gx = tx0 - PAD + lx;
            float s = 0.0f, s2 = 0.0f;
            if ((unsigned)gy < (unsigned)H && (unsigned)gx < (unsigned)W) {
                const float* p = base + (size_t)gy * W + gx;
                float v0 = p[0];
                float v1 = p[plane];
                float v2 = p[2 * plane];
                s  = v0 + v1 + v2;
                s2 = fmaf(v0, v0, fmaf(v1, v1, v2 * v2));
            }
            sh_t [idx] = s;
            sh_t2[idx] = s2;
        }
        __syncthreads();

        // Phase 2: horizontal 7-tap (rows keep halo in y)
        for (int idx = tid; idx < HT * TS; idx += NT) {
            int ly = idx / TS, lx = idx - ly * TS;
            const float* r  = &sh_t [ly * HT + lx];
            const float* r2 = &sh_t2[ly * HT + lx];
            float s = 0.0f, s2 = 0.0f;
            #pragma unroll
            for (int k = 0; k < K; ++k) { s += r[k]; s2 += r2[k]; }
            sh_h [idx] = s;
            sh_h2[idx] = s2;
        }
        __syncthreads();

        // Phase 3: vertical 7-tap + std (+ fused smooth-L1 on second input)
        for (int idx = tid; idx < TS * TS; idx += NT) {
            int ly = idx >> 5, lx = idx & 31;
            float s = 0.0f, s2 = 0.0f;
            #pragma unroll
            for (int k = 0; k < K; ++k) {
                s  += sh_h [(ly + k) * TS + lx];
                s2 += sh_h2[(ly + k) * TS + lx];
            }
            float mu  = s * INV_N;
            float var = fmaf(-mu, mu, s2 * INV_N);  // E[x^2] - mu^2
            float sd  = sqrtf(var + 1e-8f);
            if (which == 0) {
                sh_sd[idx] = sd;
            } else {
                float d  = sh_sd[idx] - sd;
                float ad = fabsf(d);
                acc += (ad < 1.0f) ? 0.5f * d * d : (ad - 0.5f);
            }
        }
        __syncthreads();
    }

    // Block reduction: wave64 shuffle, then cross-wave via LDS
    #pragma unroll
    for (int off = 32; off > 0; off >>= 1)
        acc += __shfl_down(acc, off, 64);

    __shared__ float wave_sums[NT / 64];
    if ((tid & 63) == 0) wave_sums[tid >> 6] = acc;
    __syncthreads();
    if (tid == 0) {
        float s = 0.0f;
        #pragma unroll
        for (int w = 0; w < NT / 64; ++w) s += wave_sums[w];
        atomicAdd(out, s * INV_TOTAL);
    }
}

extern "C" void kernel_launch(void* const* d_in, const int* in_sizes, int n_in,
                              void* d_out, int out_size, void* d_ws, size_t ws_size,
                              hipStream_t stream) {
    const float* pred = (const float*)d_in[0];
    const float* tgt  = (const float*)d_in[1];
    float* out = (float*)d_out;

    // d_out is poisoned 0xAA before every timed launch; the atomic needs 0.
    hipMemsetAsync(out, 0, sizeof(float), stream);

    dim3 grid(512 / TS, 512 / TS, 16);  // 16 x 16 x 16 = 4096 blocks
    dist_loss_kernel<<<grid, NT, 0, stream>>>(pred, tgt, out);
}

// Round 2
// 160.587 us; speedup vs baseline: 1.0723x; 1.0723x over previous
//
#include <hip/hip_runtime.h>

// DistributionLoss: local 7x7xC std (zero-padded) of two [16,3,512,512] fp32
// tensors, smooth-L1 mean between std maps -> scalar.
//
// R1: fully vectorized separable box filter.
//  - 64x16 output tile, 72x22 halo tile (x padded to float4 alignment).
//  - Phase 1: aligned float4 global loads (vector fully in/out of range),
//    channel reduce -> sh_t / sh_t2 (b128 LDS writes).
//  - Phase 2: sliding-window 7-tap horizontal, 4 outputs/thread-task from
//    3 ds_read_b128.
//  - Phase 3: float4 vertical 7-tap + std; input 0 parks std tile in LDS,
//    input 1 fuses smooth-L1. Post-phase-3 barrier elided so input 1's
//    global loads overlap input 0's tail compute.

#define K    7
#define PAD  3
#define TSX  64
#define TSY  16
#define HTX  72            // covers gx in [tx0-4, tx0+68)
#define HTY  22            // covers gy in [ty0-3, ty0+19)
#define LH   68            // h-buffer stride (4-bank skew per row)
#define NT   256

__global__ __launch_bounds__(NT, 5) void dist_loss_kernel(
    const float* __restrict__ pred,
    const float* __restrict__ tgt,
    float* __restrict__ out)
{
    constexpr int   C = 3, H = 512, W = 512;
    constexpr float INV_N     = 1.0f / (C * K * K);              // 1/147
    constexpr float INV_TOTAL = 1.0f / (16.0f * 512.0f * 512.0f);

    __shared__ float sh_t [HTY][HTX];
    __shared__ float sh_t2[HTY][HTX];
    __shared__ float sh_h [HTY][LH];
    __shared__ float sh_h2[HTY][LH];
    __shared__ float sh_sd[TSY][TSX];

    const int    tid   = threadIdx.x;
    const int    tx0   = blockIdx.x * TSX;
    const int    ty0   = blockIdx.y * TSY;
    const int    b     = blockIdx.z;
    const size_t plane = (size_t)H * W;

    float acc = 0.0f;

    #pragma unroll
    for (int which = 0; which < 2; ++which) {
        const float* base = (which == 0 ? pred : tgt) + (size_t)b * C * plane;

        // ---- Phase 1: aligned float4 loads, channel reduce, store t / t2
        for (int task = tid; task < HTY * (HTX / 4); task += NT) {
            int ly = task / (HTX / 4);
            int cx = task - ly * (HTX / 4);
            int gy = ty0 - PAD + ly;
            int gx = tx0 - 4 + 4 * cx;          // 16B-aligned
            float4 s  = make_float4(0.f, 0.f, 0.f, 0.f);
            float4 s2 = make_float4(0.f, 0.f, 0.f, 0.f);
            if ((unsigned)gy < (unsigned)H && (unsigned)gx < (unsigned)W) {
                const float* rp = base + (size_t)gy * W + gx;
                float4 v0 = *(const float4*)(rp);
                float4 v1 = *(const float4*)(rp + plane);
                float4 v2 = *(const float4*)(rp + 2 * plane);
                s.x = v0.x + v1.x + v2.x;  s.y = v0.y + v1.y + v2.y;
                s.z = v0.z + v1.z + v2.z;  s.w = v0.w + v1.w + v2.w;
                s2.x = fmaf(v0.x, v0.x, fmaf(v1.x, v1.x, v2.x * v2.x));
                s2.y = fmaf(v0.y, v0.y, fmaf(v1.y, v1.y, v2.y * v2.y));
                s2.z = fmaf(v0.z, v0.z, fmaf(v1.z, v1.z, v2.z * v2.z));
                s2.w = fmaf(v0.w, v0.w, fmaf(v1.w, v1.w, v2.w * v2.w));
            }
            *(float4*)&sh_t [ly][4 * cx] = s;
            *(float4*)&sh_t2[ly][4 * cx] = s2;
        }
        __syncthreads();

        // ---- Phase 2: horizontal 7-tap, 4 outputs per task (sliding window)
        for (int task = tid; task < HTY * (TSX / 4); task += NT) {
            int ly = task >> 4;
            int x0 = (task & 15) * 4;
            {
                const float* r = &sh_t[ly][x0];
                float4 a = *(const float4*)(r);
                float4 bq = *(const float4*)(r + 4);
                float4 c = *(const float4*)(r + 8);
                float s0 = a.y + a.z + a.w + bq.x + bq.y + bq.z + bq.w;
                float s1 = s0 - a.y + c.x;
                float s2 = s1 - a.z + c.y;
                float s3 = s2 - a.w + c.z;
                *(float4*)&sh_h[ly][x0] = make_float4(s0, s1, s2, s3);
            }
            {
                const float* r = &sh_t2[ly][x0];
                float4 a = *(const float4*)(r);
                float4 bq = *(const float4*)(r + 4);
                float4 c = *(const float4*)(r + 8);
                float s0 = a.y + a.z + a.w + bq.x + bq.y + bq.z + bq.w;
                float s1 = s0 - a.y + c.x;
                float s2 = s1 - a.z + c.y;
                float s3 = s2 - a.w + c.z;
                *(float4*)&sh_h2[ly][x0] = make_float4(s0, s1, s2, s3);
            }
        }
        __syncthreads();

        // ---- Phase 3: vertical 7-tap + std, exactly 1 float4 task / thread
        {
            int ly = tid >> 4;
            int x0 = (tid & 15) * 4;
            float4 s  = make_float4(0.f, 0.f, 0.f, 0.f);
            float4 s2 = make_float4(0.f, 0.f, 0.f, 0.f);
            #pragma unroll
            for (int k = 0; k < K; ++k) {
                float4 hv  = *(const float4*)&sh_h [ly + k][x0];
                float4 hv2 = *(const float4*)&sh_h2[ly + k][x0];
                s.x += hv.x;   s.y += hv.y;   s.z += hv.z;   s.w += hv.w;
                s2.x += hv2.x; s2.y += hv2.y; s2.z += hv2.z; s2.w += hv2.w;
            }
            float sd[4];
            #pragma unroll
            for (int j = 0; j < 4; ++j) {
                float sv  = (&s.x)[j];
                float sv2 = (&s2.x)[j];
                float mu  = sv * INV_N;
                float var = fmaf(-mu, mu, sv2 * INV_N);
                sd[j] = sqrtf(var + 1e-8f);
            }
            if (which == 0) {
                *(float4*)&sh_sd[ly][x0] = make_float4(sd[0], sd[1], sd[2], sd[3]);
            } else {
                const float* prev = &sh_sd[ly][x0];
                #pragma unroll
                for (int j = 0; j < 4; ++j) {
                    float d  = prev[j] - sd[j];
                    float ad = fabsf(d);
                    acc += (ad < 1.0f) ? 0.5f * d * d : (ad - 0.5f);
                }
            }
        }
        // NOTE: no barrier here — next phase 1 only writes sh_t/sh_t2, whose
        // last readers were fenced by the post-phase-2 barrier. This lets
        // input 1's global loads start while input 0's phase 3 drains.
    }

    // ---- Block reduction: wave64 shuffle, then cross-wave via LDS
    #pragma unroll
    for (int off = 32; off > 0; off >>= 1)
        acc += __shfl_down(acc, off, 64);

    __shared__ float wave_sums[NT / 64];
    if ((tid & 63) == 0) wave_sums[tid >> 6] = acc;
    __syncthreads();
    if (tid == 0) {
        float s = 0.0f;
        #pragma unroll
        for (int w = 0; w < NT / 64; ++w) s += wave_sums[w];
        atomicAdd(out, s * INV_TOTAL);
    }
}

extern "C" void kernel_launch(void* const* d_in, const int* in_sizes, int n_in,
                              void* d_out, int out_size, void* d_ws, size_t ws_size,
                              hipStream_t stream) {
    const float* pred = (const float*)d_in[0];
    const float* tgt  = (const float*)d_in[1];
    float* out = (float*)d_out;

    hipMemsetAsync(out, 0, sizeof(float), stream);

    dim3 grid(512 / TSX, 512 / TSY, 16);   // 8 x 32 x 16 = 4096 blocks
    dist_loss_kernel<<<grid, NT, 0, stream>>>(pred, tgt, out);
}